// Round 11
// baseline (101.893 us; speedup 1.0000x reference)
//
#include <hip/hip_runtime.h>

#define N_ROWS   500000
#define N_TERMS  64
#define N_OUT    4
#define TILE_R   64
#define NTILES   ((N_ROWS + TILE_R - 1) / TILE_R)     // 7813 (last tile: 32 rows)
#define F4_TOTAL (N_ROWS * (N_TERMS / 4))             // 8,000,000 float4s of thetas
#define PART_STRIDE (N_TERMS * N_TERMS + N_TERMS * N_OUT)  // 4352 floats per partial
#define NB_MAX   1024
#define CHUNKS   16
#define JACOBI_ITERS 20

typedef float f32x4   __attribute__((ext_vector_type(4)));
typedef short bf16x8  __attribute__((ext_vector_type(8)));

// LDS-only workgroup barrier (no vmcnt drain) — keeps copy-out stores and
// prefetch loads in flight across the barrier.
__device__ inline void wg_barrier_lds() {
  asm volatile("s_waitcnt lgkmcnt(0)\n\ts_barrier" ::: "memory");
}

__device__ inline unsigned short f32_bf16(float f) {      // RNE f32 -> bf16 bits
  unsigned int u = __builtin_bit_cast(unsigned int, f);
  u += 0x7fffu + ((u >> 16) & 1u);
  return (unsigned short)(u >> 16);
}

// Read an 8-deep column fragment as bf16x8. LDS tile is [64][64] fp32 with
// bit-4 column XOR swizzle per 8-row group (same validated construction).
__device__ inline bf16x8 frag_col(const float* __restrict__ Tf, int cswz, int k0) {
  bf16x8 r;
#pragma unroll
  for (int j = 0; j < 8; ++j)
    r[j] = (short)f32_bf16(Tf[(k0 + j) * 64 + cswz]);
  return r;
}

__device__ inline void load_tile(int t, const float4* __restrict__ th4,
                                 const float4* __restrict__ td4, int tid,
                                 float4 cur[2], float4& ycur) {
#pragma unroll
  for (int k = 0; k < 2; ++k) {
    int idx = t * 1024 + k * 512 + tid;
    cur[k] = (idx < F4_TOTAL) ? th4[idx] : make_float4(0.f, 0.f, 0.f, 0.f);
  }
  ycur = make_float4(0.f, 0.f, 0.f, 0.f);
  if (tid < TILE_R) {
    int row = t * TILE_R + tid;
    if (row < N_ROWS) ycur = td4[row];
  }
}

// K1: fused copy-out + bf16-MFMA Gram + fp32 Xty. 512 thr, 64-row tiles.
// Occupancy experiment: 17 KB LDS + launch_bounds(512,8) + 1024 blocks
// -> 4 blocks/CU (32 waves/CU); staggered blocks keep loads in flight.
// 8 waves = 4 output quadrants (32x32) x 2 K-halves (32 rows each).
__global__ __launch_bounds__(512, 8) void k1_gram(const float* __restrict__ th,
                                                  const float* __restrict__ td,
                                                  float* __restrict__ out_copy,
                                                  float* __restrict__ part) {
  __shared__ float4 Tlds[1024];   // 64 rows x 64 cols fp32, col-swizzled (16 KB)
  __shared__ float4 Ylds[64];     // 64 rows x 4 fp32 (1 KB)

  const int tid  = threadIdx.x;
  const int wv   = tid >> 6;
  const int lane = tid & 63;

  const int q  = wv & 3;          // output quadrant
  const int h  = wv >> 2;         // K-half (0: rows<32, 1: rows>=32)
  const int ti = q >> 1;          // quadrant row block (x32)
  const int tj = q & 1;           // quadrant col block (x32)
  const int l15 = lane & 15;
  const int kg  = (lane >> 4) * 8;          // fragment k sub-offset
  const int kb  = h * 32 + kg;              // fragment row base
  const int sz  = ((kb >> 3) & 1) << 4;     // column swizzle for this k-group
  const int cA  = ti * 32 + l15;            // A columns (rows of C)
  const int cB  = tj * 32 + l15;            // B columns (cols of C)

  f32x4 g00 = {0.f, 0.f, 0.f, 0.f}, g01 = g00, g10 = g00, g11 = g00;
  float accY[4] = {0.f, 0.f, 0.f, 0.f};

  const float4* th4 = (const float4*)th;
  const float4* td4 = (const float4*)td;
  float4* out4 = (float4*)out_copy;
  const float* Tf = (const float*)Tlds;

  const int stride = gridDim.x;
  int t = blockIdx.x;
  float4 cur[2], ycur;
  load_tile(t, th4, td4, tid, cur, ycur);

  while (true) {
    // stage current tile into LDS (col-swizzled) + fused copy-out
#pragma unroll
    for (int k = 0; k < 2; ++k) {
      const int fi  = k * 512 + tid;                 // float4 index in tile
      const int swz = ((fi >> 7) & 1) << 2;          // row bit3 -> col4 bit2
      Tlds[(fi & ~15) | ((fi & 15) ^ swz)] = cur[k];
      const int idx = t * 1024 + fi;
      if (idx < F4_TOTAL) out4[idx] = cur[k];
    }
    if (tid < TILE_R) Ylds[tid] = ycur;
    wg_barrier_lds();

    const int tn = t + stride;
    const bool more = (tn < NTILES);
    float4 nxt[2], ynxt;
    if (more) load_tile(tn, th4, td4, tid, nxt, ynxt);   // prefetch overlaps compute

    // Gram quadrant via MFMA: one k-step of 32 (K-half h)
    {
      bf16x8 a0 = frag_col(Tf, (cA)      ^ sz, kb);
      bf16x8 a1 = frag_col(Tf, (cA + 16) ^ sz, kb);
      bf16x8 b0 = frag_col(Tf, (cB)      ^ sz, kb);
      bf16x8 b1 = frag_col(Tf, (cB + 16) ^ sz, kb);
      g00 = __builtin_amdgcn_mfma_f32_16x16x32_bf16(a0, b0, g00, 0, 0, 0);
      g01 = __builtin_amdgcn_mfma_f32_16x16x32_bf16(a0, b1, g01, 0, 0, 0);
      g10 = __builtin_amdgcn_mfma_f32_16x16x32_bf16(a1, b0, g10, 0, 0, 0);
      g11 = __builtin_amdgcn_mfma_f32_16x16x32_bf16(a1, b1, g11, 0, 0, 0);
    }

    // Xty in fp32: wave owns rows wv*8..+7 of the tile
#pragma unroll
    for (int rr = 0; rr < 8; ++rr) {
      const int r = wv * 8 + rr;
      const float tv = Tf[r * 64 + (lane ^ (((r >> 3) & 1) << 4))];
      const float4 yv = Ylds[r];
      accY[0] += tv * yv.x;
      accY[1] += tv * yv.y;
      accY[2] += tv * yv.z;
      accY[3] += tv * yv.w;
    }
    wg_barrier_lds();

    if (!more) break;
    t = tn;
#pragma unroll
    for (int k = 0; k < 2; ++k) cur[k] = nxt[k];
    ycur = ynxt;
  }

  // ---- epilogue: merge K-halves, reduce Xty, write partial ----
  __syncthreads();
  float* red  = (float*)Tlds;   // 4096 f32, LINEAR [64][64] (Tlds reused)
  float* yred = (float*)Ylds;   // 256 f32  (Ylds reused)

  // C/D layout (m89-verified): col = lane&15, row = (lane>>4)*4 + reg
  const int r0 = ti * 32 + (lane >> 4) * 4;
  const int c0 = tj * 32 + l15;
  if (h == 1) {
#pragma unroll
    for (int r = 0; r < 4; ++r) {
      const int e = (r0 + r) * 64 + c0;
      red[e]            = g00[r];
      red[e + 16]       = g01[r];
      red[e + 16 * 64]      = g10[r];
      red[e + 16 * 64 + 16] = g11[r];
    }
  }
  __syncthreads();
  if (h == 0) {
#pragma unroll
    for (int r = 0; r < 4; ++r) {
      const int e = (r0 + r) * 64 + c0;
      red[e]            += g00[r];
      red[e + 16]       += g01[r];
      red[e + 16 * 64]      += g10[r];
      red[e + 16 * 64 + 16] += g11[r];
    }
  }
  __syncthreads();

  // serialized wave reduction of Xty (deterministic)
  for (int w = 0; w < 8; ++w) {
    if (wv == w) {
#pragma unroll
      for (int c = 0; c < 4; ++c) {
        if (w == 0) yred[lane * 4 + c] = accY[c];
        else        yred[lane * 4 + c] += accY[c];
      }
    }
    __syncthreads();
  }

  float* p = part + blockIdx.x * PART_STRIDE;
#pragma unroll
  for (int s = 0; s < 8; ++s) {
    const int e = s * 512 + tid;
    p[e] = red[e];                 // red is linear [64][64] — direct copy
  }
  if (tid < 256) p[4096 + tid] = yred[tid];
}

// K2a: nb partials -> 16 chunk sums (fixed order)
__global__ __launch_bounds__(256) void k2a_reduce(const float* __restrict__ part,
                                                  float* __restrict__ mid,
                                                  int per_chunk) {
  const int eblk = blockIdx.x % 17;
  const int bch  = blockIdx.x / 17;
  const int e = eblk * 256 + threadIdx.x;
  if (e >= PART_STRIDE) return;
  const float* base = part + (size_t)bch * per_chunk * PART_STRIDE + e;
  float s = 0.f;
  for (int i = 0; i < per_chunk; ++i) s += base[i * PART_STRIDE];
  mid[bch * PART_STRIDE + e] = s;
}

// K3: final reduce (16 chunks) + Jacobi solve of XtX * coeffs = Xty.
// XtX ~ N*(I+E), rho(E)~0.023 -> 20 Jacobi iters >> fp32 noise.
__global__ __launch_bounds__(256) void k3_solve(const float* __restrict__ mid,
                                                float* __restrict__ coef_out) {
  __shared__ float A[64 * 65];
  __shared__ float bX[64 * 4];
  __shared__ float X0[64 * 4];
  __shared__ float X1[64 * 4];
  const int tid = threadIdx.x;

#pragma unroll
  for (int s = 0; s < 17; ++s) {
    const int e = s * 256 + tid;
    if (e < PART_STRIDE) {
      float v = 0.f;
#pragma unroll
      for (int c = 0; c < CHUNKS; ++c) v += mid[c * PART_STRIDE + e];
      if (e < 4096) A[(e >> 6) * 65 + (e & 63)] = v;
      else          bX[e - 4096] = v;
    }
  }
  __syncthreads();

  const int i = tid >> 2;
  const int c = tid & 3;

  float arow[64];
#pragma unroll
  for (int j = 0; j < 64; ++j) arow[j] = A[i * 65 + j];

  const float dinv = 1.0f / A[i * 65 + i];   // LDS read: keeps arow[] in registers
  const float b = bX[i * 4 + c];

  float x0 = b * dinv;
  X0[tid] = x0;
  __syncthreads();

  float xlast = x0;
  for (int it = 0; it < JACOBI_ITERS; ++it) {
    const float* Xr = (it & 1) ? X1 : X0;
    float*       Xw = (it & 1) ? X0 : X1;
    float s0 = 0.f, s1 = 0.f, s2 = 0.f, s3 = 0.f;
#pragma unroll
    for (int j = 0; j < 64; j += 4) {
      s0 += arow[j]     * Xr[(j)     * 4 + c];
      s1 += arow[j + 1] * Xr[(j + 1) * 4 + c];
      s2 += arow[j + 2] * Xr[(j + 2) * 4 + c];
      s3 += arow[j + 3] * Xr[(j + 3) * 4 + c];
    }
    const float s = (s0 + s1) + (s2 + s3);
    xlast = xlast + (b - s) * dinv;
    Xw[tid] = xlast;
    __syncthreads();
  }

  coef_out[tid] = xlast;
}

extern "C" void kernel_launch(void* const* d_in, const int* in_sizes, int n_in,
                              void* d_out, int out_size, void* d_ws, size_t ws_size,
                              hipStream_t stream) {
  const float* th = (const float*)d_in[0];   // [500000, 64] fp32
  const float* td = (const float*)d_in[1];   // [500000, 4]  fp32
  float* out = (float*)d_out;                // [32,000,000 copy | 256 coeffs]
  float* ws  = (float*)d_ws;

  // 1024 partials if ws allows (18.1 MB), else fall back to 512.
  const size_t need1024 = ((size_t)NB_MAX + CHUNKS) * PART_STRIDE * sizeof(float);
  const int nb = (ws_size >= need1024) ? NB_MAX : 512;

  float* part = ws;                                  // nb * 4352 floats
  float* mid  = ws + (size_t)nb * PART_STRIDE;       // CHUNKS * 4352

  hipLaunchKernelGGL(k1_gram, dim3(nb), dim3(512), 0, stream, th, td, out, part);
  hipLaunchKernelGGL(k2a_reduce, dim3(17 * CHUNKS), dim3(256), 0, stream,
                     part, mid, nb / CHUNKS);
  hipLaunchKernelGGL(k3_solve, dim3(1), dim3(256), 0, stream, mid,
                     out + (size_t)N_ROWS * N_TERMS);
}